// Round 3
// baseline (11783.451 us; speedup 1.0000x reference)
//
#include <hip/hip_runtime.h>
#include <cstdint>

#define TT 2048
#define NH 15

typedef _Float16 f16x2 __attribute__((ext_vector_type(2)));

#if __has_builtin(__builtin_amdgcn_exp2f)
#define EXP2(x) __builtin_amdgcn_exp2f(x)
#else
#define EXP2(x) exp2f(x)
#endif
#if __has_builtin(__builtin_amdgcn_rcpf)
#define RCP(x) __builtin_amdgcn_rcpf(x)
#else
#define RCP(x) (1.0f / (x))
#endif

__device__ __forceinline__ float sigm(float x) {
    return RCP(1.0f + EXP2(x * -1.4426950408889634f));
}
__device__ __forceinline__ float tanh_fast(float x) {
    return fmaf(-2.0f, RCP(1.0f + EXP2(x * 2.8853900817779268f)), 1.0f);
}

// Broadcast lane S (S<32, compile-time) within each 32-lane half of the wave.
#define BCAST(v, S) __uint_as_float(__builtin_amdgcn_ds_swizzle(__float_as_uint(v), ((S) << 5)))
// XOR-butterfly (compile-time mask M) within each 32-lane half.
#define BFLY(v, M) __uint_as_float(__builtin_amdgcn_ds_swizzle(__float_as_uint(v), (((M) << 10) | 0x1F)))

#define DO15(M) M(0) M(1) M(2) M(3) M(4) M(5) M(6) M(7) M(8) M(9) M(10) M(11) M(12) M(13) M(14)

// Layout: 32 lanes per batch element (30 active). lane = half*15 + u.
//   half 0 owns gate rows i (u) and g (30+u)    -> zA=i, zB=g
//   half 1 owns gate rows f (15+u) and o (45+u) -> zA=f, zB=o
// Weights packed f16x2 (A-row, B-row) -> 75 VGPRs, pinned via asm so the
// backend cannot re-materialize them as in-loop global gathers (R1 failure:
// VGPR=104 < 150 needed -> ~150 divergent L1 gathers per step -> 11.7 ms).
__global__ __launch_bounds__(256, 3)
void lstm3_kernel(const float* __restrict__ input,
                  const float* __restrict__ w_ih1, const float* __restrict__ w_hh1,
                  const float* __restrict__ b_ih1, const float* __restrict__ b_hh1,
                  const float* __restrict__ w_ih2, const float* __restrict__ w_hh2,
                  const float* __restrict__ b_ih2, const float* __restrict__ b_hh2,
                  const float* __restrict__ w_ih3, const float* __restrict__ w_hh3,
                  const float* __restrict__ b_ih3, const float* __restrict__ b_hh3,
                  const float* __restrict__ w_lin, const float* __restrict__ b_lin,
                  float* __restrict__ out)
{
    const int tid   = blockIdx.x * blockDim.x + threadIdx.x;
    const int wl64  = threadIdx.x & 63;
    const int lane  = threadIdx.x & 31;
    const int elem  = tid >> 5;
    const int u     = lane % 15;     // unit 0..14 (lanes 30,31 alias 0,1; unused)
    const int half  = lane / 15;     // 0,1 active; 2 = pad
    const bool on   = (half < 2);

    const int rA = half * NH + u;    // row for zA (i or f)
    const int rB = rA + 2 * NH;      // row for zB (g or o)
    const int sA = on ? rA * NH : 0;
    const int sB = on ? rB * NH : 0;

    // ---- packed lane-private weights: (A,B) f16 pairs ----
    f16x2 wp1[NH], wp2i[NH], wp2h[NH], wp3i[NH], wp3h[NH];
#pragma unroll
    for (int c = 0; c < NH; ++c) {
        wp1[c]  = f16x2{(_Float16)(on ? w_hh1[sA + c] : 0.f), (_Float16)(on ? w_hh1[sB + c] : 0.f)};
        wp2i[c] = f16x2{(_Float16)(on ? w_ih2[sA + c] : 0.f), (_Float16)(on ? w_ih2[sB + c] : 0.f)};
        wp2h[c] = f16x2{(_Float16)(on ? w_hh2[sA + c] : 0.f), (_Float16)(on ? w_hh2[sB + c] : 0.f)};
        wp3i[c] = f16x2{(_Float16)(on ? w_ih3[sA + c] : 0.f), (_Float16)(on ? w_ih3[sB + c] : 0.f)};
        wp3h[c] = f16x2{(_Float16)(on ? w_hh3[sA + c] : 0.f), (_Float16)(on ? w_hh3[sB + c] : 0.f)};
    }
    // Pin each packed weight in a VGPR: forbid re-materialization from memory.
#pragma unroll
    for (int c = 0; c < NH; ++c) {
        uint32_t t;
        t = __builtin_bit_cast(uint32_t, wp1[c]);  asm volatile("" : "+v"(t)); wp1[c]  = __builtin_bit_cast(f16x2, t);
        t = __builtin_bit_cast(uint32_t, wp2i[c]); asm volatile("" : "+v"(t)); wp2i[c] = __builtin_bit_cast(f16x2, t);
        t = __builtin_bit_cast(uint32_t, wp2h[c]); asm volatile("" : "+v"(t)); wp2h[c] = __builtin_bit_cast(f16x2, t);
        t = __builtin_bit_cast(uint32_t, wp3i[c]); asm volatile("" : "+v"(t)); wp3i[c] = __builtin_bit_cast(f16x2, t);
        t = __builtin_bit_cast(uint32_t, wp3h[c]); asm volatile("" : "+v"(t)); wp3h[c] = __builtin_bit_cast(f16x2, t);
    }

    // small fp32 constants
    const float wiA = on ? w_ih1[rA] : 0.f;
    const float wiB = on ? w_ih1[rB] : 0.f;
    const float bA1 = on ? (b_ih1[rA] + b_hh1[rA]) : 0.f;
    const float bB1 = on ? (b_ih1[rB] + b_hh1[rB]) : 0.f;
    const float bA2 = on ? (b_ih2[rA] + b_hh2[rA]) : 0.f;
    const float bB2 = on ? (b_ih2[rB] + b_hh2[rB]) : 0.f;
    const float bA3 = on ? (b_ih3[rA] + b_hh3[rA]) : 0.f;
    const float bB3 = on ? (b_ih3[rB] + b_hh3[rB]) : 0.f;
    // zB activation: half0 -> tanh(z)=2*sigm(2z)-1 ; half1 -> sigm(z)
    const float kScl = (half == 0) ? 2.f : 1.f;
    const float kMul = (half == 0) ? 2.f : 1.f;
    const float kAdd = (half == 0) ? -1.f : 0.f;
    const float wlv  = (half == 1) ? w_lin[u] : 0.f;
    const float blv  = b_lin[0];

    // product shuffle: lane reads i*g of its unit from half0 lane u (own 32-group)
    const int pvaddr = (((wl64 & 32) | u) << 2);
    const int xbase  = ((wl64 & 32) << 2);

    float h1 = 0.f, c1 = 0.f, h2 = 0.f, c2 = 0.f, h3 = 0.f, c3 = 0.f;

    const float* xp = input + (size_t)elem * TT;
    float* op = out + (size_t)elem * TT;

#define CELL1_C(c) { const float hb = BCAST(h1, 15 + (c)); \
    zA = fmaf((float)wp1[(c)].x, hb, zA); \
    zB = fmaf((float)wp1[(c)].y, hb, zB); }
#define CELL2_C(c) { const float hb = BCAST(h1, 15 + (c)); const float gb = BCAST(h2, 15 + (c)); \
    zA = fmaf((float)wp2i[(c)].x, hb, fmaf((float)wp2h[(c)].x, gb, zA)); \
    zB = fmaf((float)wp2i[(c)].y, hb, fmaf((float)wp2h[(c)].y, gb, zB)); }
#define CELL3_C(c) { const float hb = BCAST(h2, 15 + (c)); const float gb = BCAST(h3, 15 + (c)); \
    zA = fmaf((float)wp3i[(c)].x, hb, fmaf((float)wp3h[(c)].x, gb, zA)); \
    zB = fmaf((float)wp3i[(c)].y, hb, fmaf((float)wp3h[(c)].y, gb, zB)); }
#define GATE_COMBINE(hS, cS) { \
    const float aA = sigm(zA); \
    const float aB = fmaf(kMul, sigm(kScl * zB), kAdd); \
    const float p  = aA * aB; \
    const float pv = __int_as_float(__builtin_amdgcn_ds_bpermute(pvaddr, __float_as_int(p))); \
    cS = fmaf(aA, cS, pv); \
    hS = aB * tanh_fast(cS); }

    for (int t0 = 0; t0 < TT; t0 += 32) {
        const float xt = xp[t0 + lane];   // coalesced 32-step input tile
        float ysel = 0.f;
#pragma unroll 1
        for (int tt = 0; tt < 32; ++tt) {
            const float x = __int_as_float(
                __builtin_amdgcn_ds_bpermute(xbase + (tt << 2), __float_as_int(xt)));

            // cell 1
            float zA = fmaf(wiA, x, bA1);
            float zB = fmaf(wiB, x, bB1);
            DO15(CELL1_C)
            GATE_COMBINE(h1, c1)

            // cell 2
            zA = bA2; zB = bB2;
            DO15(CELL2_C)
            GATE_COMBINE(h2, c2)

            // cell 3
            zA = bA3; zB = bB3;
            DO15(CELL3_C)
            GATE_COMBINE(h3, c3)

            // linear head: sum over half1 lanes of this 32-group
            float q = wlv * h3;
            q += BFLY(q, 1);
            q += BFLY(q, 2);
            q += BFLY(q, 4);
            q += BFLY(q, 8);
            q += BFLY(q, 16);
            const float yv = q + blv;
            ysel = (tt == lane) ? yv : ysel;
        }
        op[t0 + lane] = ysel;             // coalesced 32-step output tile
    }
#undef CELL1_C
#undef CELL2_C
#undef CELL3_C
#undef GATE_COMBINE
}

extern "C" void kernel_launch(void* const* d_in, const int* in_sizes, int n_in,
                              void* d_out, int out_size, void* d_ws, size_t ws_size,
                              hipStream_t stream) {
    const float* input = (const float*)d_in[0];
    const float* w_ih1 = (const float*)d_in[1];
    const float* w_hh1 = (const float*)d_in[2];
    const float* b_ih1 = (const float*)d_in[3];
    const float* b_hh1 = (const float*)d_in[4];
    const float* w_ih2 = (const float*)d_in[5];
    const float* w_hh2 = (const float*)d_in[6];
    const float* b_ih2 = (const float*)d_in[7];
    const float* b_hh2 = (const float*)d_in[8];
    const float* w_ih3 = (const float*)d_in[9];
    const float* w_hh3 = (const float*)d_in[10];
    const float* b_ih3 = (const float*)d_in[11];
    const float* b_hh3 = (const float*)d_in[12];
    const float* w_lin = (const float*)d_in[13];
    const float* b_lin = (const float*)d_in[14];
    float* out = (float*)d_out;

    const int B = in_sizes[0] / TT;              // 8192
    const int threads = 256;
    const int blocks = (B * 32) / threads;       // 1024

    lstm3_kernel<<<blocks, threads, 0, stream>>>(
        input, w_ih1, w_hh1, b_ih1, b_hh1,
        w_ih2, w_hh2, b_ih2, b_hh2,
        w_ih3, w_hh3, b_ih3, b_hh3,
        w_lin, b_lin, out);
}

// Round 4
// 7301.159 us; speedup vs baseline: 1.6139x; 1.6139x over previous
//
#include <hip/hip_runtime.h>
#include <cstdint>

#define TT 2048
#define NH 15

typedef _Float16 f16x2 __attribute__((ext_vector_type(2)));

#if __has_builtin(__builtin_amdgcn_exp2f)
#define EXP2(x) __builtin_amdgcn_exp2f(x)
#else
#define EXP2(x) exp2f(x)
#endif
#if __has_builtin(__builtin_amdgcn_rcpf)
#define RCP(x) __builtin_amdgcn_rcpf(x)
#else
#define RCP(x) (1.0f / (x))
#endif

#if __has_builtin(__builtin_amdgcn_fdot2)
#define FDOT2(a, b, c) __builtin_amdgcn_fdot2((a), (b), (c), false)
#else
#define FDOT2(a, b, c) fmaf((float)(a).x, (float)(b).x, fmaf((float)(a).y, (float)(b).y, (c)))
#endif

#if __has_builtin(__builtin_amdgcn_cvt_pkrtz)
#define PKRTZ(a, b) __builtin_amdgcn_cvt_pkrtz((a), (b))
#else
#define PKRTZ(a, b) (f16x2{(_Float16)(a), (_Float16)(b)})
#endif

// ds_swizzle BitMode: broadcast lane S within each 32-lane half.
#define BCASTF(v, S) __uint_as_float(__builtin_amdgcn_ds_swizzle(__float_as_uint(v), ((S) << 5)))
#define BCASTU(v, S) __builtin_amdgcn_ds_swizzle((int)(v), ((S) << 5))
// XOR-butterfly within each 32-lane half.
#define BFLY(v, M) __uint_as_float(__builtin_amdgcn_ds_swizzle(__float_as_uint(v), (((M) << 10) | 0x1F)))

#define DO15(M) M(0) M(1) M(2) M(3) M(4) M(5) M(6) M(7) M(8) M(9) M(10) M(11) M(12) M(13) M(14)

// Layout: 32 lanes per batch element (30 active). lane = half*15 + u.
//   half 0 owns gate rows i (u) and g (30+u)    -> zA=i, zB=g
//   half 1 owns gate rows f (15+u) and o (45+u) -> zA=f, zB=o
// h/c state valid on half-1 lanes (lane 15+u); half-0 state is dead-but-computed.
//
// amdgpu_waves_per_eu(3,3): R1/R2 showed the pressure scheduler spills to chase
// its DEFAULT max occupancy (8 waves/EU -> 64-VGPR target); launch_bounds only
// raises the min. Pinning max=3 gives a 170-VGPR budget for the ~135-reg live set.
__global__ __launch_bounds__(256) __attribute__((amdgpu_waves_per_eu(3, 3)))
void lstm3_kernel(const float* __restrict__ input,
                  const float* __restrict__ w_ih1, const float* __restrict__ w_hh1,
                  const float* __restrict__ b_ih1, const float* __restrict__ b_hh1,
                  const float* __restrict__ w_ih2, const float* __restrict__ w_hh2,
                  const float* __restrict__ b_ih2, const float* __restrict__ b_hh2,
                  const float* __restrict__ w_ih3, const float* __restrict__ w_hh3,
                  const float* __restrict__ b_ih3, const float* __restrict__ b_hh3,
                  const float* __restrict__ w_lin, const float* __restrict__ b_lin,
                  float* __restrict__ out)
{
    const int tid   = blockIdx.x * blockDim.x + threadIdx.x;
    const int wl64  = threadIdx.x & 63;
    const int lane  = threadIdx.x & 31;
    const int elem  = tid >> 5;
    const int u     = lane % 15;     // unit 0..14 (lanes 30,31 alias 0,1; results unused)
    const int half  = lane / 15;     // 0,1 active; 2 = pad
    const bool on   = (half < 2);

    const int rA = half * NH + u;    // gate row for zA (i or f)
    const int rB = rA + 2 * NH;      // gate row for zB (g or o)
    const int sA = on ? rA * NH : 0;
    const int sB = on ? rB * NH : 0;

    // ---- lane-private weights ----
    float w1A[NH], w1B[NH];          // cell1 W_hh rows, fp32
    f16x2 w2A[NH], w2B[NH];          // cells 2/3: (w_ih, w_hh) packed per column
    f16x2 w3A[NH], w3B[NH];
#pragma unroll
    for (int c = 0; c < NH; ++c) {
        w1A[c] = on ? w_hh1[sA + c] : 0.f;
        w1B[c] = on ? w_hh1[sB + c] : 0.f;
        w2A[c] = f16x2{(_Float16)(on ? w_ih2[sA + c] : 0.f), (_Float16)(on ? w_hh2[sA + c] : 0.f)};
        w2B[c] = f16x2{(_Float16)(on ? w_ih2[sB + c] : 0.f), (_Float16)(on ? w_hh2[sB + c] : 0.f)};
        w3A[c] = f16x2{(_Float16)(on ? w_ih3[sA + c] : 0.f), (_Float16)(on ? w_hh3[sA + c] : 0.f)};
        w3B[c] = f16x2{(_Float16)(on ? w_ih3[sB + c] : 0.f), (_Float16)(on ? w_hh3[sB + c] : 0.f)};
    }

    const float wiA = on ? w_ih1[rA] : 0.f;
    const float wiB = on ? w_ih1[rB] : 0.f;
    const float bA1 = on ? (b_ih1[rA] + b_hh1[rA]) : 0.f;
    const float bB1 = on ? (b_ih1[rB] + b_hh1[rB]) : 0.f;
    const float bA2 = on ? (b_ih2[rA] + b_hh2[rA]) : 0.f;
    const float bB2 = on ? (b_ih2[rB] + b_hh2[rB]) : 0.f;
    const float bA3 = on ? (b_ih3[rA] + b_hh3[rA]) : 0.f;
    const float bB3 = on ? (b_ih3[rB] + b_hh3[rB]) : 0.f;
    // zB activation: half0 -> tanh(z)=2*sigm(2z)-1 ; half1 -> sigm(z)
    const float kScl = (half == 0) ? 2.f : 1.f;
    const float kAdd = (half == 0) ? -1.f : 0.f;
    const float wlv  = (half == 1) ? w_lin[u] : 0.f;
    const float blv  = b_lin[0];

    // i*g product fetch: every lane reads half0 lane u of its own 32-group
    const int pvaddr = (((wl64 & 32) | u) << 2);
    const int xbase  = ((wl64 & 32) << 2);

    float h1 = 0.f, c1 = 0.f, h2 = 0.f, c2 = 0.f, h3 = 0.f, c3 = 0.f;

    const float* xp = input + (size_t)elem * TT;
    float* op = out + (size_t)elem * TT;

__device__ float sigm_dummy(); // (unused; keeps some toolchains from inlining-reordering warnings)

#define SIGM(x) (RCP(1.0f + EXP2((x) * -1.4426950408889634f)))
#define TANHF(x) (fmaf(-2.0f, RCP(1.0f + EXP2((x) * 2.8853900817779268f)), 1.0f))

#define CELL1_C(c) { const float hb = BCASTF(h1, 15 + (c)); \
    zA = fmaf(w1A[(c)], hb, zA); \
    zB = fmaf(w1B[(c)], hb, zB); }
#define CELL2_C(c) { const f16x2 hp = __builtin_bit_cast(f16x2, BCASTU(ph, 15 + (c))); \
    zA = FDOT2(w2A[(c)], hp, zA); \
    zB = FDOT2(w2B[(c)], hp, zB); }
#define CELL3_C(c) { const f16x2 hp = __builtin_bit_cast(f16x2, BCASTU(ph, 15 + (c))); \
    zA = FDOT2(w3A[(c)], hp, zA); \
    zB = FDOT2(w3B[(c)], hp, zB); }
#define GATE_COMBINE(hS, cS) { \
    const float aA = SIGM(zA); \
    const float aB = fmaf(kScl, SIGM(kScl * zB), kAdd); \
    const float p  = aA * aB; \
    const float pv = __int_as_float(__builtin_amdgcn_ds_bpermute(pvaddr, __float_as_int(p))); \
    cS = fmaf(aA, cS, pv); \
    hS = aB * TANHF(cS); }

    for (int t0 = 0; t0 < TT; t0 += 32) {
        const float xt = xp[t0 + lane];   // coalesced 32-step input tile
        float ysel = 0.f;
#pragma unroll 1
        for (int tt = 0; tt < 32; ++tt) {
            const float x = __int_as_float(
                __builtin_amdgcn_ds_bpermute(xbase + (tt << 2), __float_as_int(xt)));

            // ---- cell 1 (fp32 h1 recurrence) ----
            float zA = fmaf(wiA, x, bA1);
            float zB = fmaf(wiB, x, bB1);
            DO15(CELL1_C)
            GATE_COMBINE(h1, c1)

            // ---- cell 2: pack (h1_new, h2_old) once, 1 swizzle + 2 dot2 per column ----
            {
                const int ph = __builtin_bit_cast(short2, PKRTZ(h1, h2)).x |
                               (__builtin_bit_cast(short2, PKRTZ(h1, h2)).y << 16);
                (void)ph;
            }
            int ph = __builtin_bit_cast(int, PKRTZ(h1, h2));
            zA = bA2; zB = bB2;
            DO15(CELL2_C)
            GATE_COMBINE(h2, c2)

            // ---- cell 3: pack (h2_new, h3_old) ----
            ph = __builtin_bit_cast(int, PKRTZ(h2, h3));
            zA = bA3; zB = bB3;
            DO15(CELL3_C)
            GATE_COMBINE(h3, c3)

            // ---- linear head: sum over half1 lanes of this 32-group ----
            float q = wlv * h3;
            q += BFLY(q, 1);
            q += BFLY(q, 2);
            q += BFLY(q, 4);
            q += BFLY(q, 8);
            q += BFLY(q, 16);
            const float yv = q + blv;
            ysel = (tt == lane) ? yv : ysel;
        }
        op[t0 + lane] = ysel;             // coalesced 32-step output tile
    }
#undef CELL1_C
#undef CELL2_C
#undef CELL3_C
#undef GATE_COMBINE
}

extern "C" void kernel_launch(void* const* d_in, const int* in_sizes, int n_in,
                              void* d_out, int out_size, void* d_ws, size_t ws_size,
                              hipStream_t stream) {
    const float* input = (const float*)d_in[0];
    const float* w_ih1 = (const float*)d_in[1];
    const float* w_hh1 = (const float*)d_in[2];
    const float* b_ih1 = (const float*)d_in[3];
    const float* b_hh1 = (const float*)d_in[4];
    const float* w_ih2 = (const float*)d_in[5];
    const float* w_hh2 = (const float*)d_in[6];
    const float* b_ih2 = (const float*)d_in[7];
    const float* b_hh2 = (const float*)d_in[8];
    const float* w_ih3 = (const float*)d_in[9];
    const float* w_hh3 = (const float*)d_in[10];
    const float* b_ih3 = (const float*)d_in[11];
    const float* b_hh3 = (const float*)d_in[12];
    const float* w_lin = (const float*)d_in[13];
    const float* b_lin = (const float*)d_in[14];
    float* out = (float*)d_out;

    const int B = in_sizes[0] / TT;              // 8192
    const int threads = 256;
    const int blocks = (B * 32) / threads;       // 1024

    lstm3_kernel<<<blocks, threads, 0, stream>>>(
        input, w_ih1, w_hh1, b_ih1, b_hh1,
        w_ih2, w_hh2, b_ih2, b_hh2,
        w_ih3, w_hh3, b_ih3, b_hh3,
        w_lin, b_lin, out);
}

// Round 5
// 3852.695 us; speedup vs baseline: 3.0585x; 1.8951x over previous
//
#include <hip/hip_runtime.h>
#include <cstdint>

#define TT 2048
#define NH 15

typedef _Float16 f16x2 __attribute__((ext_vector_type(2)));

#if __has_builtin(__builtin_amdgcn_exp2f)
#define EXP2(x) __builtin_amdgcn_exp2f(x)
#else
#define EXP2(x) exp2f(x)
#endif
#if __has_builtin(__builtin_amdgcn_rcpf)
#define RCP(x) __builtin_amdgcn_rcpf(x)
#else
#define RCP(x) (1.0f / (x))
#endif

#if __has_builtin(__builtin_amdgcn_fdot2)
#define FDOT2(a, b, c) __builtin_amdgcn_fdot2((a), (b), (c), false)
#else
#define FDOT2(a, b, c) fmaf((float)(a).x, (float)(b).x, fmaf((float)(a).y, (float)(b).y, (c)))
#endif

#if __has_builtin(__builtin_amdgcn_cvt_pkrtz)
#define PKRTZ(a, b) __builtin_amdgcn_cvt_pkrtz((a), (b))
#else
#define PKRTZ(a, b) (f16x2{(_Float16)(a), (_Float16)(b)})
#endif

// ds_swizzle BitMode: broadcast lane S within each 32-lane half of the wave.
#define BCASTU(v, S) __builtin_amdgcn_ds_swizzle((int)(v), ((S) << 5))
// XOR-butterfly within each 32-lane half.
#define BFLY(v, M) __uint_as_float(__builtin_amdgcn_ds_swizzle(__float_as_uint(v), (((M) << 10) | 0x1F)))

#define DO15(M) M(0) M(1) M(2) M(3) M(4) M(5) M(6) M(7) M(8) M(9) M(10) M(11) M(12) M(13) M(14)

// Layout: 32 lanes per batch-element GROUP; each group now carries TWO batch
// elements (a,b) sharing one weight set. lane = half*15 + u:
//   half 0 owns gate rows i (u) and g (30+u)    -> zA=i, zB=g
//   half 1 owns gate rows f (15+u) and o (45+u) -> zA=f, zB=o
// h/c state valid on half-1 lanes.
//
// R4 forensics: VGPR=68, FETCH/WRITE ideal -> compiler REMATERIALIZES weight
// loads from L1 every step (remat is free in its cost model at any budget).
// Fix: (a) waves_per_eu(2,2) -> pressure target 256 regs; (b) opaque asm on
// loaded weights -> remat impossible; (c) 2 elems/group -> 2x chains, weights
// amortized.
__global__ __launch_bounds__(256) __attribute__((amdgpu_waves_per_eu(2, 2)))
void lstm3_kernel(const float* __restrict__ input,
                  const float* __restrict__ w_ih1, const float* __restrict__ w_hh1,
                  const float* __restrict__ b_ih1, const float* __restrict__ b_hh1,
                  const float* __restrict__ w_ih2, const float* __restrict__ w_hh2,
                  const float* __restrict__ b_ih2, const float* __restrict__ b_hh2,
                  const float* __restrict__ w_ih3, const float* __restrict__ w_hh3,
                  const float* __restrict__ b_ih3, const float* __restrict__ b_hh3,
                  const float* __restrict__ w_lin, const float* __restrict__ b_lin,
                  float* __restrict__ out, int nGrp)
{
    const int tid   = blockIdx.x * blockDim.x + threadIdx.x;
    const int wl64  = threadIdx.x & 63;
    const int lane  = threadIdx.x & 31;
    const int grp   = tid >> 5;
    const int u     = lane % 15;     // unit 0..14 (lanes 30,31 alias 0,1; results unused)
    const int half  = lane / 15;     // 0,1 active; 2 = pad
    const bool on   = (half < 2);

    const int rA = half * NH + u;    // gate row for zA (i or f)
    const int rB = rA + 2 * NH;      // gate row for zB (g or o)
    const int sA = on ? rA * NH : 0;
    const int sB = on ? rB * NH : 0;

    // ---- lane-private weights ----
    f16x2 w1p[NH];                   // cell1 W_hh: (rowA, rowB) packed
    f16x2 w2A[NH], w2B[NH];          // cells 2/3: (w_ih, w_hh) packed per column
    f16x2 w3A[NH], w3B[NH];
#pragma unroll
    for (int c = 0; c < NH; ++c) {
        w1p[c] = f16x2{(_Float16)(on ? w_hh1[sA + c] : 0.f), (_Float16)(on ? w_hh1[sB + c] : 0.f)};
        w2A[c] = f16x2{(_Float16)(on ? w_ih2[sA + c] : 0.f), (_Float16)(on ? w_hh2[sA + c] : 0.f)};
        w2B[c] = f16x2{(_Float16)(on ? w_ih2[sB + c] : 0.f), (_Float16)(on ? w_hh2[sB + c] : 0.f)};
        w3A[c] = f16x2{(_Float16)(on ? w_ih3[sA + c] : 0.f), (_Float16)(on ? w_hh3[sA + c] : 0.f)};
        w3B[c] = f16x2{(_Float16)(on ? w_ih3[sB + c] : 0.f), (_Float16)(on ? w_hh3[sB + c] : 0.f)};
    }
    // Opaque pin: asm results cannot be rematerialized from memory.
#pragma unroll
    for (int c = 0; c < NH; ++c) {
        uint32_t t;
        t = __builtin_bit_cast(uint32_t, w1p[c]); asm("" : "+v"(t)); w1p[c] = __builtin_bit_cast(f16x2, t);
        t = __builtin_bit_cast(uint32_t, w2A[c]); asm("" : "+v"(t)); w2A[c] = __builtin_bit_cast(f16x2, t);
        t = __builtin_bit_cast(uint32_t, w2B[c]); asm("" : "+v"(t)); w2B[c] = __builtin_bit_cast(f16x2, t);
        t = __builtin_bit_cast(uint32_t, w3A[c]); asm("" : "+v"(t)); w3A[c] = __builtin_bit_cast(f16x2, t);
        t = __builtin_bit_cast(uint32_t, w3B[c]); asm("" : "+v"(t)); w3B[c] = __builtin_bit_cast(f16x2, t);
    }

    const float wiA = on ? w_ih1[rA] : 0.f;
    const float wiB = on ? w_ih1[rB] : 0.f;
    const float bA1 = on ? (b_ih1[rA] + b_hh1[rA]) : 0.f;
    const float bB1 = on ? (b_ih1[rB] + b_hh1[rB]) : 0.f;
    const float bA2 = on ? (b_ih2[rA] + b_hh2[rA]) : 0.f;
    const float bB2 = on ? (b_ih2[rB] + b_hh2[rB]) : 0.f;
    const float bA3 = on ? (b_ih3[rA] + b_hh3[rA]) : 0.f;
    const float bB3 = on ? (b_ih3[rB] + b_hh3[rB]) : 0.f;
    // zB activation: half0 -> tanh(z)=2*sigm(2z)-1 ; half1 -> sigm(z)
    const float kScl = (half == 0) ? 2.f : 1.f;
    const float kAdd = (half == 0) ? -1.f : 0.f;
    const float wlv  = (half == 1) ? w_lin[u] : 0.f;
    const float blv  = b_lin[0];

    // i*g product fetch: every lane reads half0 lane u of its own 32-group
    const int pvaddr = (((wl64 & 32) | u) << 2);
    const int xbase  = ((wl64 & 32) << 2);

    // ---- state: two elements (a, b) per group ----
    float h1a = 0.f, c1a = 0.f, h2a = 0.f, c2a = 0.f, h3a = 0.f, c3a = 0.f;
    float h1b = 0.f, c1b = 0.f, h2b = 0.f, c2b = 0.f, h3b = 0.f, c3b = 0.f;

    const float* xpa = input + (size_t)grp * TT;
    const float* xpb = input + (size_t)(grp + nGrp) * TT;
    float* opa = out + (size_t)grp * TT;
    float* opb = out + (size_t)(grp + nGrp) * TT;

#define SIGM(x) (RCP(1.0f + EXP2((x) * -1.4426950408889634f)))
#define TANHF(x) (fmaf(-2.0f, RCP(1.0f + EXP2((x) * 2.8853900817779268f)), 1.0f))

// cell1: one swizzle of (h1a,h1b) pack serves both elems; fma_mix accumulate
#define CELL1_C(c) { const f16x2 hp = __builtin_bit_cast(f16x2, BCASTU(ph, 15 + (c))); \
    zAa = fmaf((float)w1p[(c)].x, (float)hp.x, zAa); \
    zAb = fmaf((float)w1p[(c)].x, (float)hp.y, zAb); \
    zBa = fmaf((float)w1p[(c)].y, (float)hp.x, zBa); \
    zBb = fmaf((float)w1p[(c)].y, (float)hp.y, zBb); }
// cells 2/3: per-elem (h_prev,h_own) pack; 2 swizzles + 4 dot2 per column
#define CELL23_C(W_A, W_B, c) { \
    const f16x2 hpa = __builtin_bit_cast(f16x2, BCASTU(pha, 15 + (c))); \
    const f16x2 hpb = __builtin_bit_cast(f16x2, BCASTU(phb, 15 + (c))); \
    zAa = FDOT2(W_A[(c)], hpa, zAa); \
    zAb = FDOT2(W_A[(c)], hpb, zAb); \
    zBa = FDOT2(W_B[(c)], hpa, zBa); \
    zBb = FDOT2(W_B[(c)], hpb, zBb); }
#define CELL2_C(c) CELL23_C(w2A, w2B, c)
#define CELL3_C(c) CELL23_C(w3A, w3B, c)
#define GATE1(zA, zB, hS, cS) { \
    const float aA = SIGM(zA); \
    const float aB = fmaf(kScl, SIGM(kScl * (zB)), kAdd); \
    const float p  = aA * aB; \
    const float pv = __int_as_float(__builtin_amdgcn_ds_bpermute(pvaddr, __float_as_int(p))); \
    cS = fmaf(aA, cS, pv); \
    hS = aB * TANHF(cS); }
#define GATES(hSa, cSa, hSb, cSb) GATE1(zAa, zBa, hSa, cSa) GATE1(zAb, zBb, hSb, cSb)

    for (int t0 = 0; t0 < TT; t0 += 32) {
        const float xta = xpa[t0 + lane];   // coalesced 32-step input tiles
        const float xtb = xpb[t0 + lane];
        float ysela = 0.f, yselb = 0.f;
#pragma unroll 1
        for (int tt = 0; tt < 32; ++tt) {
            const int xaddr = xbase + (tt << 2);
            const float xa = __int_as_float(__builtin_amdgcn_ds_bpermute(xaddr, __float_as_int(xta)));
            const float xb = __int_as_float(__builtin_amdgcn_ds_bpermute(xaddr, __float_as_int(xtb)));

            // ---- cell 1 ----
            const int ph = __builtin_bit_cast(int, PKRTZ(h1a, h1b));
            float zAa = fmaf(wiA, xa, bA1), zAb = fmaf(wiA, xb, bA1);
            float zBa = fmaf(wiB, xa, bB1), zBb = fmaf(wiB, xb, bB1);
            DO15(CELL1_C)
            GATES(h1a, c1a, h1b, c1b)

            // ---- cell 2 ----
            {
                const int pha = __builtin_bit_cast(int, PKRTZ(h1a, h2a));
                const int phb = __builtin_bit_cast(int, PKRTZ(h1b, h2b));
                zAa = bA2; zAb = bA2; zBa = bB2; zBb = bB2;
                DO15(CELL2_C)
                GATES(h2a, c2a, h2b, c2b)
            }

            // ---- cell 3 ----
            {
                const int pha = __builtin_bit_cast(int, PKRTZ(h2a, h3a));
                const int phb = __builtin_bit_cast(int, PKRTZ(h2b, h3b));
                zAa = bA3; zAb = bA3; zBa = bB3; zBb = bB3;
                DO15(CELL3_C)
                GATES(h3a, c3a, h3b, c3b)
            }

            // ---- linear head: butterfly sum within each 32-group ----
            float qa = wlv * h3a;
            float qb = wlv * h3b;
            qa += BFLY(qa, 1);  qb += BFLY(qb, 1);
            qa += BFLY(qa, 2);  qb += BFLY(qb, 2);
            qa += BFLY(qa, 4);  qb += BFLY(qb, 4);
            qa += BFLY(qa, 8);  qb += BFLY(qb, 8);
            qa += BFLY(qa, 16); qb += BFLY(qb, 16);
            ysela = (tt == lane) ? (qa + blv) : ysela;
            yselb = (tt == lane) ? (qb + blv) : yselb;
        }
        opa[t0 + lane] = ysela;             // coalesced 32-step output tiles
        opb[t0 + lane] = yselb;
    }
#undef CELL1_C
#undef CELL23_C
#undef CELL2_C
#undef CELL3_C
#undef GATE1
#undef GATES
}

extern "C" void kernel_launch(void* const* d_in, const int* in_sizes, int n_in,
                              void* d_out, int out_size, void* d_ws, size_t ws_size,
                              hipStream_t stream) {
    const float* input = (const float*)d_in[0];
    const float* w_ih1 = (const float*)d_in[1];
    const float* w_hh1 = (const float*)d_in[2];
    const float* b_ih1 = (const float*)d_in[3];
    const float* b_hh1 = (const float*)d_in[4];
    const float* w_ih2 = (const float*)d_in[5];
    const float* w_hh2 = (const float*)d_in[6];
    const float* b_ih2 = (const float*)d_in[7];
    const float* b_hh2 = (const float*)d_in[8];
    const float* w_ih3 = (const float*)d_in[9];
    const float* w_hh3 = (const float*)d_in[10];
    const float* b_ih3 = (const float*)d_in[11];
    const float* b_hh3 = (const float*)d_in[12];
    const float* w_lin = (const float*)d_in[13];
    const float* b_lin = (const float*)d_in[14];
    float* out = (float*)d_out;

    const int B = in_sizes[0] / TT;              // 8192
    const int nGrp = B / 2;                      // 4096 groups, 2 elems each
    const int threads = 256;
    const int blocks = (nGrp * 32) / threads;    // 512

    lstm3_kernel<<<blocks, threads, 0, stream>>>(
        input, w_ih1, w_hh1, b_ih1, b_hh1,
        w_ih2, w_hh2, b_ih2, b_hh2,
        w_ih3, w_hh3, b_ih3, b_hh3,
        w_lin, b_lin, out, nGrp);
}

// Round 6
// 3040.400 us; speedup vs baseline: 3.8756x; 1.2672x over previous
//
#include <hip/hip_runtime.h>
#include <cstdint>

#define TT 2048
#define NH 15

typedef _Float16 half8 __attribute__((ext_vector_type(8)));
typedef _Float16 f16x2 __attribute__((ext_vector_type(2)));
typedef float f32x4 __attribute__((ext_vector_type(4)));
typedef int int4v __attribute__((ext_vector_type(4)));

#define EXP2(x) __builtin_amdgcn_exp2f(x)
#define RCP(x) __builtin_amdgcn_rcpf(x)
#define SIGM(x) (RCP(1.0f + EXP2((x) * -1.4426950408889634f)))
#define TANHF(x) (fmaf(-2.0f, RCP(1.0f + EXP2((x) * 2.8853900817779268f)), 1.0f))
#define BPERM(addr, v) __builtin_amdgcn_ds_bpermute((addr), (v))
#define PKRTZ_I(a, b) __builtin_bit_cast(int, __builtin_amdgcn_cvt_pkrtz((a), (b)))

// MFMA formulation. One wave = 16 batch elements, all 3 cells, all T steps.
// Per cell: Z[64x16] = Wp[64x32] x V[32x16], 4x mfma_f32_16x16x32_f16.
// Wp row layout (M): gate-major, each gate padded to 16 rows: m = unit (0..14),
//   m=15 pad (zero rows -> z_pad=0 -> h_pad stays 0). Gate tile g: i,f,g,o.
// V row layout (K):
//   cell1:  k0-14 = h1_prev, k15 = x_t (A col15 = w_ih1), k16 = 1.0 (A col16 =
//           bias), k17-31 = 0.
//   cell2/3: k0-14 = h_in (new h from prev cell), k15 = don't-care (A col15=0),
//           k16-30 = h_own (prev step), k31 = 1.0 (A col31 = bias).
// Fragment maps (m89-verified): A[m=lane&15][k=(lane>>4)*8+j]; B[k][n=lane&15],
// same k map; D col=lane&15, row=(lane>>4)*4+r. So lane (q,n) owns gates
// i,f,g,o of units {4q+r} for element n -> c/h update is lane-local; only the
// h -> next-B step needs 4-8 ds_bpermute (fixed quad permutation).
__global__ __launch_bounds__(64) __attribute__((amdgpu_waves_per_eu(1, 1)))
void lstm3_mfma(const float* __restrict__ input,
                const float* __restrict__ w_ih1, const float* __restrict__ w_hh1,
                const float* __restrict__ b_ih1, const float* __restrict__ b_hh1,
                const float* __restrict__ w_ih2, const float* __restrict__ w_hh2,
                const float* __restrict__ b_ih2, const float* __restrict__ b_hh2,
                const float* __restrict__ w_ih3, const float* __restrict__ w_hh3,
                const float* __restrict__ b_ih3, const float* __restrict__ b_hh3,
                const float* __restrict__ w_lin, const float* __restrict__ b_lin,
                float* __restrict__ out)
{
    const int lane = threadIdx.x & 63;
    const int n = lane & 15;          // element (B-col) AND unit-row (A-m) index
    const int q = lane >> 4;          // quad
    const bool qlt2 = (q < 2);
    // B-build source addresses: dest dwords (d0,d1) pull from src quad 2*(q&1),
    // (d2,d3) from quad 2*(q&1)+1, same column n. (bpermute addr = lane*4)
    const int addrA = (((q & 1) * 32) + n) * 4;
    const int addrB = addrA + 64;

    // ---- A fragments (static, f16, 48 VGPRs) ----
    half8 a1[4], a2[4], a3[4];
#pragma unroll
    for (int g = 0; g < 4; ++g) {
        half8 t1 = {}, t2 = {}, t3 = {};
#pragma unroll
        for (int j = 0; j < 8; ++j) {
            const int k = q * 8 + j;
            float v1 = 0.f, v2 = 0.f, v3 = 0.f;
            if (n < NH) {   // m = n; pad row m=15 stays zero
                const int r = g * NH + n;
                v1 = (k < NH) ? w_hh1[r * NH + k]
                   : (k == NH) ? w_ih1[r]
                   : (k == 16) ? (b_ih1[r] + b_hh1[r]) : 0.f;
                v2 = (k < NH) ? w_ih2[r * NH + k]
                   : (k >= 16 && k < 31) ? w_hh2[r * NH + (k - 16)]
                   : (k == 31) ? (b_ih2[r] + b_hh2[r]) : 0.f;
                v3 = (k < NH) ? w_ih3[r * NH + k]
                   : (k >= 16 && k < 31) ? w_hh3[r * NH + (k - 16)]
                   : (k == 31) ? (b_ih3[r] + b_hh3[r]) : 0.f;
            }
            t1[j] = (_Float16)v1; t2[j] = (_Float16)v2; t3[j] = (_Float16)v3;
        }
        a1[g] = t1; a2[g] = t2; a3[g] = t3;
    }

    // head weights: partial dot over this lane's 4 units
    float wl[4];
#pragma unroll
    for (int r = 0; r < 4; ++r) {
        const int u = 4 * q + r;
        wl[r] = (u < NH) ? w_lin[u] : 0.f;
    }
    const float blv = b_lin[0];

    const f32x4 z4 = {0.f, 0.f, 0.f, 0.f};

    // ---- state: lane (q,n) holds units 4q+r of element n ----
    float h1f[4] = {0.f, 0.f, 0.f, 0.f}, c1f[4] = {0.f, 0.f, 0.f, 0.f};
    float h2f[4] = {0.f, 0.f, 0.f, 0.f}, c2f[4] = {0.f, 0.f, 0.f, 0.f};
    float h3f[4] = {0.f, 0.f, 0.f, 0.f}, c3f[4] = {0.f, 0.f, 0.f, 0.f};

    const float* xrow = input + (size_t)(blockIdx.x * 16 + n) * TT;
    float* orow = out + (size_t)(blockIdx.x * 16 + n) * TT;

#define CELL_UPDATE(A, Bf, HF, CF) { \
    f32x4 d0 = __builtin_amdgcn_mfma_f32_16x16x32_f16(A[0], (Bf), z4, 0, 0, 0); \
    f32x4 d1 = __builtin_amdgcn_mfma_f32_16x16x32_f16(A[1], (Bf), z4, 0, 0, 0); \
    f32x4 d2 = __builtin_amdgcn_mfma_f32_16x16x32_f16(A[2], (Bf), z4, 0, 0, 0); \
    f32x4 d3 = __builtin_amdgcn_mfma_f32_16x16x32_f16(A[3], (Bf), z4, 0, 0, 0); \
    _Pragma("unroll") \
    for (int r = 0; r < 4; ++r) { \
        const float iv = SIGM(d0[r]); \
        const float fv = SIGM(d1[r]); \
        const float gv = TANHF(d2[r]); \
        const float ov = SIGM(d3[r]); \
        CF[r] = fmaf(fv, CF[r], iv * gv); \
        HF[r] = ov * TANHF(CF[r]); \
    } }

    float xcur = xrow[q];   // steps t0..t0+3 live in quads 0..3

    for (int t0 = 0; t0 < TT; t0 += 4) {
        const int tnx = (t0 + 4 < TT) ? (t0 + 4 + q) : q;
        const float xnext = xrow[tnx];      // prefetch next 4-step tile
        float ysel = 0.f;
#pragma unroll 1
        for (int ph = 0; ph < 4; ++ph) {
            // broadcast x_t to all lanes of column n
            const float xv = __int_as_float(
                BPERM((ph * 16 + n) * 4, __float_as_int(xcur)));

            // ---- cell 1: B rows = [h1_prev(15), x, 1(bias), 0...] ----
            {
                const int p0 = PKRTZ_I(h1f[0], h1f[1]);
                const int p1 = PKRTZ_I(h1f[2], (q == 3) ? xv : h1f[3]);
                const int b0 = qlt2 ? BPERM(addrA, p0) : ((q == 2) ? 0x3C00 : 0);
                const int b1 = qlt2 ? BPERM(addrA, p1) : 0;
                const int b2 = qlt2 ? BPERM(addrB, p0) : 0;
                const int b3 = qlt2 ? BPERM(addrB, p1) : 0;
                const int4v bi = {b0, b1, b2, b3};
                const half8 Bf = __builtin_bit_cast(half8, bi);
                CELL_UPDATE(a1, Bf, h1f, c1f)
            }

            // ---- cell 2: B rows = [h1_new, -, h2_old, 1(bias)] ----
            {
                const int i0 = PKRTZ_I(h1f[0], h1f[1]);
                const int i1 = PKRTZ_I(h1f[2], h1f[3]);
                const int o0 = PKRTZ_I(h2f[0], h2f[1]);
                const int o1 = PKRTZ_I(h2f[2], (q == 3) ? 1.0f : h2f[3]);
                const int b0 = qlt2 ? BPERM(addrA, i0) : BPERM(addrA, o0);
                const int b1 = qlt2 ? BPERM(addrA, i1) : BPERM(addrA, o1);
                const int b2 = qlt2 ? BPERM(addrB, i0) : BPERM(addrB, o0);
                const int b3 = qlt2 ? BPERM(addrB, i1) : BPERM(addrB, o1);
                const int4v bi = {b0, b1, b2, b3};
                const half8 Bf = __builtin_bit_cast(half8, bi);
                CELL_UPDATE(a2, Bf, h2f, c2f)
            }

            // ---- cell 3: B rows = [h2_new, -, h3_old, 1(bias)] ----
            {
                const int i0 = PKRTZ_I(h2f[0], h2f[1]);
                const int i1 = PKRTZ_I(h2f[2], h2f[3]);
                const int o0 = PKRTZ_I(h3f[0], h3f[1]);
                const int o1 = PKRTZ_I(h3f[2], (q == 3) ? 1.0f : h3f[3]);
                const int b0 = qlt2 ? BPERM(addrA, i0) : BPERM(addrA, o0);
                const int b1 = qlt2 ? BPERM(addrA, i1) : BPERM(addrA, o1);
                const int b2 = qlt2 ? BPERM(addrB, i0) : BPERM(addrB, o0);
                const int b3 = qlt2 ? BPERM(addrB, i1) : BPERM(addrB, o1);
                const int4v bi = {b0, b1, b2, b3};
                const half8 Bf = __builtin_bit_cast(half8, bi);
                CELL_UPDATE(a3, Bf, h3f, c3f)
            }

            // ---- linear head: y[n] = sum_u wl[u] h3[u][n] + b ----
            float p = fmaf(wl[0], h3f[0],
                      fmaf(wl[1], h3f[1],
                      fmaf(wl[2], h3f[2], wl[3] * h3f[3])));
            p += __shfl_xor(p, 16, 64);   // sum across quads (same column n)
            p += __shfl_xor(p, 32, 64);
            ysel = (q == ph) ? (p + blv) : ysel;
        }
        orow[t0 + q] = ysel;              // lane (q,n) stores out[n][t0+q]
        xcur = xnext;
    }
#undef CELL_UPDATE
}

extern "C" void kernel_launch(void* const* d_in, const int* in_sizes, int n_in,
                              void* d_out, int out_size, void* d_ws, size_t ws_size,
                              hipStream_t stream) {
    const float* input = (const float*)d_in[0];
    const float* w_ih1 = (const float*)d_in[1];
    const float* w_hh1 = (const float*)d_in[2];
    const float* b_ih1 = (const float*)d_in[3];
    const float* b_hh1 = (const float*)d_in[4];
    const float* w_ih2 = (const float*)d_in[5];
    const float* w_hh2 = (const float*)d_in[6];
    const float* b_ih2 = (const float*)d_in[7];
    const float* b_hh2 = (const float*)d_in[8];
    const float* w_ih3 = (const float*)d_in[9];
    const float* w_hh3 = (const float*)d_in[10];
    const float* b_ih3 = (const float*)d_in[11];
    const float* b_hh3 = (const float*)d_in[12];
    const float* w_lin = (const float*)d_in[13];
    const float* b_lin = (const float*)d_in[14];
    float* out = (float*)d_out;

    const int B = in_sizes[0] / TT;      // 8192
    const int blocks = B / 16;           // 512 waves, 16 elems each

    lstm3_mfma<<<blocks, 64, 0, stream>>>(
        input, w_ih1, w_hh1, b_ih1, b_hh1,
        w_ih2, w_hh2, b_ih2, b_hh2,
        w_ih3, w_hh3, b_ih3, b_hh3,
        w_lin, b_lin, out);
}